// Round 4
// baseline (524.868 us; speedup 1.0000x reference)
//
#include <hip/hip_runtime.h>

#define NB 32
#define NC 512
#define NH 56
#define NW 56
#define HW 3136       // 56*56
#define CHW 1605632   // 512*3136
#define CPB 16        // planes (channels) per block in k12

// ---- K12: fused mask + channel max/sum accumulation (replaces K1 + K2a) ----
// grid = NB * (NC/CPB) = 1024 blocks; block (b, chunk) streams CPB contiguous
// planes. Register-resident accumulators: thread t owns spatial positions
// {4i..4i+3 : i in {t, t+256, t+512} U ({t+768} if t<16)} — identical index
// set for every plane, so channel max/sum accumulate in regs, no LDS staging.
// cmax/csum must be pre-zeroed; merged via atomics at block end.
// NOTE: csum lives in d_out scratch (k4 overwrites d_out last), keeping ws
// usage at the previously harness-verified 648 KB footprint.
__global__ __launch_bounds__(256) void k12_maskbb(const float* __restrict__ x,
                                                  float* __restrict__ mask,
                                                  float* __restrict__ cmax,
                                                  double* __restrict__ csum) {
    const int b = blockIdx.x >> 5;
    const int c0 = (blockIdx.x & 31) * CPB;
    const int tid = threadIdx.x;
    __shared__ double rsum[4];
    __shared__ float rmax[4];
    const bool has4 = (tid < 16);   // 784 float4s = 3*256 + 16
    float am[16];
    double as[16];
#pragma unroll
    for (int k = 0; k < 16; k++) { am[k] = 0.f; as[k] = 0.0; }

    for (int p = 0; p < CPB; p++) {
        const float4* px = (const float4*)(x + (size_t)(b * NC + c0 + p) * HW);
        float v[16];
#pragma unroll
        for (int k = 0; k < 4; k++) {
            if (k < 3 || has4) {
                float4 t = px[tid + k * 256];
                v[4 * k + 0] = fmaxf(t.x, 0.f);
                v[4 * k + 1] = fmaxf(t.y, 0.f);
                v[4 * k + 2] = fmaxf(t.z, 0.f);
                v[4 * k + 3] = fmaxf(t.w, 0.f);
            } else {
                v[4 * k + 0] = 0.f; v[4 * k + 1] = 0.f;
                v[4 * k + 2] = 0.f; v[4 * k + 3] = 0.f;
            }
        }
        // per-thread reduce in the same order as the verified K1 chain
        float lmax = 0.f;
        double lsum = 0.0;
#pragma unroll
        for (int k = 0; k < 16; k++) {
            lmax = fmaxf(lmax, v[k]);
            lsum += (double)v[k];
        }
        for (int off = 32; off; off >>= 1) {
            lsum += __shfl_xor(lsum, off);
            lmax = fmaxf(lmax, __shfl_xor(lmax, off));
        }
        __syncthreads();   // rsum/rmax free from previous iteration's readers
        if ((tid & 63) == 0) { rsum[tid >> 6] = lsum; rmax[tid >> 6] = lmax; }
        __syncthreads();
        // every thread computes the block-uniform mask (no broadcast sync)
        double s = rsum[0] + rsum[1] + rsum[2] + rsum[3];
        float m = fmaxf(fmaxf(rmax[0], rmax[1]), fmaxf(rmax[2], rmax[3]));
        float avg = (float)(s / 3136.0);
        float mk = ((m - avg) < 0.5f) ? 0.f : 1.f;
        if (tid == 0) mask[b * NC + c0 + p] = mk;
        if (mk != 0.f) {
#pragma unroll
            for (int k = 0; k < 16; k++) {
                am[k] = fmaxf(am[k], v[k]);
                as[k] += (double)v[k];
            }
        }
    }
    const size_t gb = (size_t)b * HW;
#pragma unroll
    for (int k = 0; k < 4; k++) {
        if (k < 3 || has4) {
            const int pos = 4 * (tid + k * 256);
#pragma unroll
            for (int j = 0; j < 4; j++) {
                float mv = am[4 * k + j];
                if (mv > 0.f)
                    atomicMax((int*)(cmax + gb + pos + j), __float_as_int(mv));
                double sv = as[4 * k + j];
                if (sv != 0.0) atomicAdd(csum + gb + pos + j, sv);
            }
        }
    }
}

// ---- K2bb: finalize bb = 1 - exp(-|cmax - csum/512|), bb overwrites cmax ----
__global__ __launch_bounds__(256) void k2bb_fin(float* __restrict__ cmaxbb,
                                                const double* __restrict__ csum) {
    int i = blockIdx.x * 256 + threadIdx.x;   // grid*block == NB*HW exactly
    float m = cmaxbb[i];
    double cmean = csum[i] * (1.0 / 512.0);
    double d = fabs((double)m - cmean);
    cmaxbb[i] = (float)(1.0 - exp(-d));
}

// ---- K2b: per-(b,c) plane: x_max and pooled of x2 = bb*x1 (one block) ----
__global__ __launch_bounds__(256) void k2b_stats(const float* __restrict__ x,
                                                 const float* __restrict__ mask,
                                                 const float* __restrict__ bb,
                                                 float* __restrict__ xmax,
                                                 float* __restrict__ pooled) {
    const int plane = blockIdx.x;  // b*512 + c
    const int b = plane >> 9;
    const float4* px = (const float4*)(x + (size_t)plane * HW);
    const float4* pbb = (const float4*)(bb + (size_t)b * HW);
    const float mk = mask[plane];
    float m = 0.f;
    double s = 0.0;
    for (int i = threadIdx.x; i < HW / 4; i += 256) {
        float4 v = px[i];
        float4 bv = pbb[i];
        float x0 = fmaxf(v.x, 0.f) * mk * bv.x;  // identical fp32 chain as K4
        float x1 = fmaxf(v.y, 0.f) * mk * bv.y;
        float x2 = fmaxf(v.z, 0.f) * mk * bv.z;
        float x3 = fmaxf(v.w, 0.f) * mk * bv.w;
        m = fmaxf(m, fmaxf(fmaxf(x0, x1), fmaxf(x2, x3)));
        s += (double)x0 + (double)x1 + (double)x2 + (double)x3;
    }
    for (int off = 32; off; off >>= 1) {
        s += __shfl_xor(s, off);
        m = fmaxf(m, __shfl_xor(m, off));
    }
    __shared__ double ssum[4];
    __shared__ float smax[4];
    int wid = threadIdx.x >> 6, lane = threadIdx.x & 63;
    if (lane == 0) { ssum[wid] = s; smax[wid] = m; }
    __syncthreads();
    if (threadIdx.x == 0) {
        double st = ssum[0] + ssum[1] + ssum[2] + ssum[3];
        float mt = fmaxf(fmaxf(smax[0], smax[1]), fmaxf(smax[2], smax[3]));
        xmax[plane] = mt;
        pooled[plane] = (float)(st / 3136.0);
    }
}

// ------------- K3: FC gates (wave-per-output dot products) -> thres -------------
__global__ __launch_bounds__(256) void k3_gates(const float* __restrict__ pooled,
                                                const float* __restrict__ W1,
                                                const float* __restrict__ W3,
                                                const float* __restrict__ xmax,
                                                float* __restrict__ thres) {
    int wave = threadIdx.x >> 6, lane = threadIdx.x & 63;
    int task0 = (blockIdx.x * 4 + wave) * 4;
    for (int t = 0; t < 4; t++) {
        int task = task0 + t;                       // b*512 + j
        int b = task >> 9, j = task & 511;
        const float* r1 = W1 + j * 512;
        const float* r3 = W3 + j * 512;
        const float* pr = pooled + b * 512;
        double s1 = 0.0, s3 = 0.0;
        for (int k = lane; k < 512; k += 64) {
            double p = (double)pr[k];
            s1 += p * (double)r1[k];
            s3 += p * (double)r3[k];
        }
        for (int off = 32; off; off >>= 1) {
            s1 += __shfl_xor(s1, off);
            s3 += __shfl_xor(s3, off);
        }
        if (lane == 0) {
            float c1 = (float)(1.0 / (1.0 + exp(-s1)));   // sigmoid
            double r = s3 > 0.0 ? s3 : 0.0;               // relu
            float c3 = (float)((r < 1.0) ? 1.2 : r);
            thres[task] = c1 * c3 * xmax[task];           // np's fp32 mul order
        }
    }
}

// ---------------- K4: recompute x2, threshold, write fp32 out ----------------
__global__ __launch_bounds__(256) void k4_out(const float* __restrict__ x,
                                              const float* __restrict__ mask,
                                              const float* __restrict__ bb,
                                              const float* __restrict__ thres,
                                              float* __restrict__ out) {
    const int plane = blockIdx.x;
    const int b = plane >> 9;
    const float4* px = (const float4*)(x + (size_t)plane * HW);
    float4* po = (float4*)(out + (size_t)plane * HW);
    const float4* pbb = (const float4*)(bb + (size_t)b * HW);
    const float th = thres[plane];
    const float mk = mask[plane];
    for (int i = threadIdx.x; i < HW / 4; i += 256) {
        float4 v = px[i];
        float4 bv = pbb[i];
        float x0 = fmaxf(v.x, 0.f) * mk * bv.x;  // identical fp32 chain as K2b
        float x1 = fmaxf(v.y, 0.f) * mk * bv.y;
        float x2 = fmaxf(v.z, 0.f) * mk * bv.z;
        float x3 = fmaxf(v.w, 0.f) * mk * bv.w;
        float4 o;
        o.x = (x0 < th) ? 0.f : x0;
        o.y = (x1 < th) ? 0.f : x1;
        o.z = (x2 < th) ? 0.f : x2;
        o.w = (x3 < th) ? 0.f : x3;
        po[i] = o;
    }
}

extern "C" void kernel_launch(void* const* d_in, const int* in_sizes, int n_in,
                              void* d_out, int out_size, void* d_ws, size_t ws_size,
                              hipStream_t stream) {
    const float* x  = (const float*)d_in[0];
    const float* W1 = (const float*)d_in[1];
    const float* W3 = (const float*)d_in[2];
    float* out = (float*)d_out;
    float* ws = (float*)d_ws;
    // ws layout (float slots) — exactly the previously harness-verified 648 KB:
    //   cmaxbb : [0, 100352)        cmax during k12, bb after k2bb (in place)
    //   mask   : [100352, 116736)
    //   xmax   : [116736, 133120)
    //   pooled : [133120, 149504)
    //   thres  : [149504, 165888)   total 663,552 B
    float* cmaxbb = ws;
    float* mask   = ws + 100352;
    float* xmax   = ws + 116736;
    float* pooled = ws + 133120;
    float* thres  = ws + 149504;
    // csum (100352 doubles = 802,816 B) lives at the START of d_out (205 MB):
    // consumed by k2bb before k4 overwrites all of d_out with the real output.
    double* csum = (double*)d_out;

    // zero cmax (ws) and csum (d_out scratch); 0-bits == 0.0 for f32/f64
    hipMemsetAsync(cmaxbb, 0, (size_t)100352 * 4, stream);
    hipMemsetAsync(csum,   0, (size_t)100352 * 8, stream);

    hipLaunchKernelGGL(k12_maskbb, dim3(NB * (NC / CPB)), dim3(256), 0, stream,
                       x, mask, cmaxbb, csum);
    hipLaunchKernelGGL(k2bb_fin,   dim3(NB * HW / 256),   dim3(256), 0, stream,
                       cmaxbb, csum);
    hipLaunchKernelGGL(k2b_stats,  dim3(NB * NC), dim3(256), 0, stream,
                       x, mask, cmaxbb, xmax, pooled);
    hipLaunchKernelGGL(k3_gates,   dim3(1024),    dim3(256), 0, stream,
                       pooled, W1, W3, xmax, thres);
    hipLaunchKernelGGL(k4_out,     dim3(NB * NC), dim3(256), 0, stream,
                       x, mask, cmaxbb, thres, out);
}

// Round 7
// 449.033 us; speedup vs baseline: 1.1689x; 1.1689x over previous
//
#include <hip/hip_runtime.h>

#define NB 32
#define NC 512
#define NH 56
#define NW 56
#define HW 3136       // 56*56
#define CHW 1605632   // 512*3136
#define CPB 16        // planes (channels) per block in k12
#define NPART 32      // NC/CPB partial chunks

// ---- K12: fused mask + channel max/sum partials (replaces K1 + K2a) ----
// grid = NB * NPART = 1024 blocks; block (b, chunk) streams CPB contiguous
// planes. Register-resident accumulators: thread t owns spatial positions
// {4i..4i+3 : i in {t, t+256, t+512} U ({t+768} if t<16)} — identical index
// set for every plane, so channel max/sum accumulate in regs, no LDS staging.
// NO atomics: each block writes its private partials coalesced into d_out
// scratch (psum f64 + pmax f32); k2bb reduces chunks deterministically.
__global__ __launch_bounds__(256) void k12_maskbb(const float* __restrict__ x,
                                                  float* __restrict__ mask,
                                                  float* __restrict__ pmax,
                                                  double* __restrict__ psum) {
    const int b = blockIdx.x >> 5;
    const int ch = blockIdx.x & 31;
    const int c0 = ch * CPB;
    const int tid = threadIdx.x;
    __shared__ double rsum[4];
    __shared__ float rmax[4];
    const bool has4 = (tid < 16);   // 784 float4s = 3*256 + 16
    float am[16];
    double as[16];
#pragma unroll
    for (int k = 0; k < 16; k++) { am[k] = 0.f; as[k] = 0.0; }

    for (int p = 0; p < CPB; p++) {
        const float4* px = (const float4*)(x + (size_t)(b * NC + c0 + p) * HW);
        float v[16];
#pragma unroll
        for (int k = 0; k < 4; k++) {
            if (k < 3 || has4) {
                float4 t = px[tid + k * 256];
                v[4 * k + 0] = fmaxf(t.x, 0.f);
                v[4 * k + 1] = fmaxf(t.y, 0.f);
                v[4 * k + 2] = fmaxf(t.z, 0.f);
                v[4 * k + 3] = fmaxf(t.w, 0.f);
            } else {
                v[4 * k + 0] = 0.f; v[4 * k + 1] = 0.f;
                v[4 * k + 2] = 0.f; v[4 * k + 3] = 0.f;
            }
        }
        // per-thread reduce in the same order as the verified K1 chain
        float lmax = 0.f;
        double lsum = 0.0;
#pragma unroll
        for (int k = 0; k < 16; k++) {
            lmax = fmaxf(lmax, v[k]);
            lsum += (double)v[k];
        }
        for (int off = 32; off; off >>= 1) {
            lsum += __shfl_xor(lsum, off);
            lmax = fmaxf(lmax, __shfl_xor(lmax, off));
        }
        __syncthreads();   // rsum/rmax free from previous iteration's readers
        if ((tid & 63) == 0) { rsum[tid >> 6] = lsum; rmax[tid >> 6] = lmax; }
        __syncthreads();
        // every thread computes the block-uniform mask (no broadcast sync)
        double s = rsum[0] + rsum[1] + rsum[2] + rsum[3];
        float m = fmaxf(fmaxf(rmax[0], rmax[1]), fmaxf(rmax[2], rmax[3]));
        float avg = (float)(s / 3136.0);
        float mk = ((m - avg) < 0.5f) ? 0.f : 1.f;
        if (tid == 0) mask[b * NC + c0 + p] = mk;
        if (mk != 0.f) {
#pragma unroll
            for (int k = 0; k < 16; k++) {
                am[k] = fmaxf(am[k], v[k]);
                as[k] += (double)v[k];
            }
        }
    }
    // coalesced private-partial writeout (no atomics)
    const size_t pb = ((size_t)ch * NB + b) * HW;
#pragma unroll
    for (int k = 0; k < 4; k++) {
        if (k < 3 || has4) {
            const int pos = 4 * (tid + k * 256);
            *(float4*)(pmax + pb + pos) =
                make_float4(am[4 * k], am[4 * k + 1], am[4 * k + 2], am[4 * k + 3]);
            *(double2*)(psum + pb + pos)     = make_double2(as[4 * k],     as[4 * k + 1]);
            *(double2*)(psum + pb + pos + 2) = make_double2(as[4 * k + 2], as[4 * k + 3]);
        }
    }
}

// ---- K2bb: reduce chunk partials (deterministic order) -> bb in ws ----
__global__ __launch_bounds__(256) void k2bb_fin(const float* __restrict__ pmax,
                                                const double* __restrict__ psum,
                                                float* __restrict__ bb) {
    const int i = blockIdx.x * 256 + threadIdx.x;  // grid*block == NB*HW exactly
    const int b = i / HW, pos = i % HW;
    float m = 0.f;
    double s = 0.0;
#pragma unroll 4
    for (int ch = 0; ch < NPART; ch++) {
        const size_t idx = ((size_t)ch * NB + b) * HW + pos;
        m = fmaxf(m, pmax[idx]);
        s += psum[idx];
    }
    double cmean = s * (1.0 / 512.0);
    double d = fabs((double)m - cmean);
    bb[i] = (float)(1.0 - exp(-d));
}

// ---- K2b: per-(b,c) plane: x_max and pooled of x2 = bb*x1 (one block) ----
__global__ __launch_bounds__(256) void k2b_stats(const float* __restrict__ x,
                                                 const float* __restrict__ mask,
                                                 const float* __restrict__ bb,
                                                 float* __restrict__ xmax,
                                                 float* __restrict__ pooled) {
    const int plane = blockIdx.x;  // b*512 + c
    const int b = plane >> 9;
    const float4* px = (const float4*)(x + (size_t)plane * HW);
    const float4* pbb = (const float4*)(bb + (size_t)b * HW);
    const float mk = mask[plane];
    float m = 0.f;
    double s = 0.0;
    for (int i = threadIdx.x; i < HW / 4; i += 256) {
        float4 v = px[i];
        float4 bv = pbb[i];
        float x0 = fmaxf(v.x, 0.f) * mk * bv.x;  // identical fp32 chain as K4
        float x1 = fmaxf(v.y, 0.f) * mk * bv.y;
        float x2 = fmaxf(v.z, 0.f) * mk * bv.z;
        float x3 = fmaxf(v.w, 0.f) * mk * bv.w;
        m = fmaxf(m, fmaxf(fmaxf(x0, x1), fmaxf(x2, x3)));
        s += (double)x0 + (double)x1 + (double)x2 + (double)x3;
    }
    for (int off = 32; off; off >>= 1) {
        s += __shfl_xor(s, off);
        m = fmaxf(m, __shfl_xor(m, off));
    }
    __shared__ double ssum[4];
    __shared__ float smax[4];
    int wid = threadIdx.x >> 6, lane = threadIdx.x & 63;
    if (lane == 0) { ssum[wid] = s; smax[wid] = m; }
    __syncthreads();
    if (threadIdx.x == 0) {
        double st = ssum[0] + ssum[1] + ssum[2] + ssum[3];
        float mt = fmaxf(fmaxf(smax[0], smax[1]), fmaxf(smax[2], smax[3]));
        xmax[plane] = mt;
        pooled[plane] = (float)(st / 3136.0);
    }
}

// ------------- K3: FC gates (wave-per-output dot products) -> thres -------------
__global__ __launch_bounds__(256) void k3_gates(const float* __restrict__ pooled,
                                                const float* __restrict__ W1,
                                                const float* __restrict__ W3,
                                                const float* __restrict__ xmax,
                                                float* __restrict__ thres) {
    int wave = threadIdx.x >> 6, lane = threadIdx.x & 63;
    int task0 = (blockIdx.x * 4 + wave) * 4;
    for (int t = 0; t < 4; t++) {
        int task = task0 + t;                       // b*512 + j
        int b = task >> 9, j = task & 511;
        const float* r1 = W1 + j * 512;
        const float* r3 = W3 + j * 512;
        const float* pr = pooled + b * 512;
        double s1 = 0.0, s3 = 0.0;
        for (int k = lane; k < 512; k += 64) {
            double p = (double)pr[k];
            s1 += p * (double)r1[k];
            s3 += p * (double)r3[k];
        }
        for (int off = 32; off; off >>= 1) {
            s1 += __shfl_xor(s1, off);
            s3 += __shfl_xor(s3, off);
        }
        if (lane == 0) {
            float c1 = (float)(1.0 / (1.0 + exp(-s1)));   // sigmoid
            double r = s3 > 0.0 ? s3 : 0.0;               // relu
            float c3 = (float)((r < 1.0) ? 1.2 : r);
            thres[task] = c1 * c3 * xmax[task];           // np's fp32 mul order
        }
    }
}

// ---------------- K4: recompute x2, threshold, write fp32 out ----------------
__global__ __launch_bounds__(256) void k4_out(const float* __restrict__ x,
                                              const float* __restrict__ mask,
                                              const float* __restrict__ bb,
                                              const float* __restrict__ thres,
                                              float* __restrict__ out) {
    const int plane = blockIdx.x;
    const int b = plane >> 9;
    const float4* px = (const float4*)(x + (size_t)plane * HW);
    float4* po = (float4*)(out + (size_t)plane * HW);
    const float4* pbb = (const float4*)(bb + (size_t)b * HW);
    const float th = thres[plane];
    const float mk = mask[plane];
    for (int i = threadIdx.x; i < HW / 4; i += 256) {
        float4 v = px[i];
        float4 bv = pbb[i];
        float x0 = fmaxf(v.x, 0.f) * mk * bv.x;  // identical fp32 chain as K2b
        float x1 = fmaxf(v.y, 0.f) * mk * bv.y;
        float x2 = fmaxf(v.z, 0.f) * mk * bv.z;
        float x3 = fmaxf(v.w, 0.f) * mk * bv.w;
        float4 o;
        o.x = (x0 < th) ? 0.f : x0;
        o.y = (x1 < th) ? 0.f : x1;
        o.z = (x2 < th) ? 0.f : x2;
        o.w = (x3 < th) ? 0.f : x3;
        po[i] = o;
    }
}

extern "C" void kernel_launch(void* const* d_in, const int* in_sizes, int n_in,
                              void* d_out, int out_size, void* d_ws, size_t ws_size,
                              hipStream_t stream) {
    const float* x  = (const float*)d_in[0];
    const float* W1 = (const float*)d_in[1];
    const float* W3 = (const float*)d_in[2];
    float* out = (float*)d_out;
    float* ws = (float*)d_ws;
    // ws layout (float slots) — same verified 648 KB footprint:
    //   bb     : [0, 100352)
    //   mask   : [100352, 116736)
    //   xmax   : [116736, 133120)
    //   pooled : [133120, 149504)
    //   thres  : [149504, 165888)   total 663,552 B
    float* bb     = ws;
    float* mask   = ws + 100352;
    float* xmax   = ws + 116736;
    float* pooled = ws + 133120;
    float* thres  = ws + 149504;
    // chunk partials live in d_out scratch (38.5 MB of 205 MB), consumed by
    // k2bb strictly before k4 overwrites d_out with the real output:
    //   psum : NPART*NB*HW doubles at offset 0        (25,690,112 B)
    //   pmax : NPART*NB*HW floats  after psum         (12,845,056 B)
    double* psum = (double*)d_out;
    float* pmax  = (float*)d_out + NPART * NB * HW * 2;  // *2: doubles->float slots

    hipLaunchKernelGGL(k12_maskbb, dim3(NB * NPART),    dim3(256), 0, stream,
                       x, mask, pmax, psum);
    hipLaunchKernelGGL(k2bb_fin,   dim3(NB * HW / 256), dim3(256), 0, stream,
                       pmax, psum, bb);
    hipLaunchKernelGGL(k2b_stats,  dim3(NB * NC), dim3(256), 0, stream,
                       x, mask, bb, xmax, pooled);
    hipLaunchKernelGGL(k3_gates,   dim3(1024),    dim3(256), 0, stream,
                       pooled, W1, W3, xmax, thres);
    hipLaunchKernelGGL(k4_out,     dim3(NB * NC), dim3(256), 0, stream,
                       x, mask, bb, thres, out);
}